// Round 1
// baseline (46462.781 us; speedup 1.0000x reference)
//
#include <hip/hip_runtime.h>
#include <hip/hip_bf16.h>
#include <cstdint>
#include <cstddef>

// Problem constants
#define BB   64
#define TT   512
#define HH   500
#define G4H  2000   // 4*H
#define KPAD 512    // recurrent K padded 500 -> 512
#define TCH  64     // timesteps per phase
#define D1P  1024   // layer-1 input dim padded 1000 -> 1024

__device__ __forceinline__ float sigm(float x) { return 1.f / (1.f + __expf(-x)); }
// NaN-safe tanh via exp (saturates cleanly at +-1)
__device__ __forceinline__ float tanh_fast(float x) {
    float e = __expf(2.f * x);
    return 1.f - 2.f / (e + 1.f);
}

// ---- prep: pad W_hh [2000][500] -> [2000][512] (zeros) for 4 (layer,dir) ----
__global__ __launch_bounds__(256) void pad_whh_kernel(
    const float* __restrict__ w0, const float* __restrict__ w1,
    const float* __restrict__ w2, const float* __restrict__ w3,
    float* __restrict__ dst)
{
    int idx = blockIdx.x * 256 + threadIdx.x;   // exactly 4*2000*512 threads
    int k = idx & (KPAD - 1);
    int rowAll = idx >> 9;                      // 0..7999
    int ld = rowAll / G4H;
    int r  = rowAll - ld * G4H;
    const float* src = (ld == 0) ? w0 : (ld == 1) ? w1 : (ld == 2) ? w2 : w3;
    dst[idx] = (k < HH) ? src[r * HH + k] : 0.f;
}

// ---- prep: pad W_ih1 [2000][1000] -> [2000][1024] for 2 dirs ----
__global__ __launch_bounds__(256) void pad_wih1_kernel(
    const float* __restrict__ wf, const float* __restrict__ wb,
    float* __restrict__ dst)
{
    int idx = blockIdx.x * 256 + threadIdx.x;   // exactly 2*2000*1024 threads
    int k = idx & (D1P - 1);
    int rowAll = idx >> 10;                     // 0..3999
    int d = rowAll / G4H;
    int r = rowAll - d * G4H;
    const float* src = d ? wb : wf;
    dst[idx] = (k < 1000) ? src[r * 1000 + k] : 0.f;
}

// ---- input-projection GEMM for one 64-timestep chunk, both dirs ----
// C[64 tl x 2000 n] = A[64 x K] @ W^T + bias, per batch b (blockIdx.x), dir (blockIdx.z)
// Wave-uniform W rows via s_load broadcast (VALU-bound, not LDS-bound).
__global__ __launch_bounds__(256, 3) void gemm_chunk_kernel(
    const float* __restrict__ A, int lda, int K,
    const float* __restrict__ Wf, const float* __restrict__ Wb,
    const float* __restrict__ bf_, const float* __restrict__ bb_,
    float* __restrict__ gates, int t0f, int t0b)
{
    const int dir = blockIdx.z;
    const float* W    = dir ? Wb  : Wf;
    const float* bias = dir ? bb_ : bf_;
    const int t0 = dir ? t0b : t0f;
    const int b  = blockIdx.x;
    const int n_base = blockIdx.y * 32;
    const int tid  = threadIdx.x;
    const int lane = tid & 63;
    const int w = __builtin_amdgcn_readfirstlane(tid >> 6);  // wave id: owns 8 n-rows

    __shared__ float As[64][66];   // [m][k], +2 pad -> ~4-way max conflicts on b64 reads
    __shared__ float Cs[64][36];   // transpose buffer for coalesced C store

    float acc[8];
    #pragma unroll
    for (int i = 0; i < 8; ++i) acc[i] = 0.f;

    const int row0   = b * TT + t0;
    const int mStage = tid >> 2;
    const int kStage = (tid & 3) << 4;

    for (int k0 = 0; k0 < K; k0 += 64) {
        // stage A tile [64 m][64 k] (coalesced global, float2 LDS stores: 66-stride rows)
        const float* ap = A + (size_t)(row0 + mStage) * lda + k0 + kStage;
        #pragma unroll
        for (int i = 0; i < 16; i += 4) {
            float4 v = *(const float4*)(ap + i);
            *(float2*)&As[mStage][kStage + i]     = make_float2(v.x, v.y);
            *(float2*)&As[mStage][kStage + i + 2] = make_float2(v.z, v.w);
        }
        __syncthreads();
        // each lane (= row m) pulls its 64 A values into VGPRs
        float a[64];
        #pragma unroll
        for (int i = 0; i < 64; i += 2) {
            float2 v = *(const float2*)&As[lane][i];
            a[i] = v.x; a[i + 1] = v.y;
        }
        __syncthreads();   // after this, next-iter staging can't race reads
        // 8 wave-uniform weight rows via scalar loads; acc[ni] gives ILP
        #pragma unroll
        for (int q = 0; q < 16; ++q) {
            #pragma unroll
            for (int ni = 0; ni < 8; ++ni) {
                const int row = n_base + w * 8 + ni;
                if (row < G4H) {
                    const float4 w4 = *(const float4*)(W + (size_t)row * K + k0 + q * 4);
                    float s = acc[ni];
                    s = fmaf(w4.x, a[q * 4 + 0], s);
                    s = fmaf(w4.y, a[q * 4 + 1], s);
                    s = fmaf(w4.z, a[q * 4 + 2], s);
                    s = fmaf(w4.w, a[q * 4 + 3], s);
                    acc[ni] = s;
                }
            }
        }
    }

    // transpose through LDS for coalesced, vectorized C stores
    #pragma unroll
    for (int ni = 0; ni < 8; ++ni) Cs[lane][w * 8 + ni] = acc[ni];
    __syncthreads();
    {
        const int m  = tid >> 2;
        const int nn = (tid & 3) << 3;
        float* gp = gates + (size_t)dir * (BB * TCH * G4H)
                          + (size_t)(b * TCH + m) * G4H + n_base + nn;
        #pragma unroll
        for (int i = 0; i < 8; i += 4) {
            const int n = n_base + nn + i;
            if (n < G4H) {
                float4 v;
                v.x = Cs[m][nn + i + 0] + bias[n + 0];
                v.y = Cs[m][nn + i + 1] + bias[n + 1];
                v.z = Cs[m][nn + i + 2] + bias[n + 2];
                v.w = Cs[m][nn + i + 3] + bias[n + 3];
                *(float4*)(gp + i) = v;
            }
        }
    }
}

// ---- one recurrence step, both dirs (blockIdx.y), 4 hidden units per WG ----
// gates_r[b] = sum_k h_prev[b][k] * W_hh[row_r][k]  via h in VGPRs + s_load W
// then i,f,g,o nonlinearities, masked c/h update, write y.
__global__ __launch_bounds__(256, 2) void lstm_step_kernel(
    const float* __restrict__ gates, const float* __restrict__ whh,
    const int* __restrict__ lengths,
    float* __restrict__ hbuf, float* __restrict__ cbuf,
    float* __restrict__ yout, int y_ld,
    int s, int p)
{
    const int dir = blockIdx.y;
    const int u0  = blockIdx.x * 4;
    const int tid = threadIdx.x;
    const int b   = tid & 63;
    const int kc  = __builtin_amdgcn_readfirstlane(tid >> 6);  // wave = k-split quarter
    const int par = s & 1;

    const int sl = s - p * TCH;
    const int t  = dir ? (TT - 1 - s) : s;
    const int tl = dir ? (TCH - 1 - sl) : sl;

    const float* Wd  = whh + (size_t)dir * G4H * KPAD;
    const float* hpL = hbuf + (size_t)((dir * 2 + par) * BB) * KPAD;   // h_prev [B][KPAD]

    // h chunk for this wave's k-range into VGPRs (pad cols are zero from memset)
    float h[128];
    {
        const float* hp = hpL + (size_t)b * KPAD + kc * 128;
        #pragma unroll
        for (int i = 0; i < 128; i += 4) {
            float4 v = *(const float4*)(hp + i);
            h[i] = v.x; h[i + 1] = v.y; h[i + 2] = v.z; h[i + 3] = v.w;
        }
    }

    float acc[16];
    #pragma unroll
    for (int r = 0; r < 16; ++r) acc[r] = 0.f;

    // 16 gate-rows (4 gates x 4 units), weights wave-uniform -> s_load_dwordx4
    #pragma unroll
    for (int q = 0; q < 32; ++q) {
        #pragma unroll
        for (int r = 0; r < 16; ++r) {
            const int row = (r >> 2) * HH + u0 + (r & 3);
            const float4 w4 = *(const float4*)(Wd + (size_t)row * KPAD + kc * 128 + q * 4);
            float sa = acc[r];
            sa = fmaf(w4.x, h[q * 4 + 0], sa);
            sa = fmaf(w4.y, h[q * 4 + 1], sa);
            sa = fmaf(w4.z, h[q * 4 + 2], sa);
            sa = fmaf(w4.w, h[q * 4 + 3], sa);
            acc[r] = sa;
        }
    }

    // cross-wave reduction (k-split partials) through LDS; 17-stride kills conflicts
    __shared__ float red[4][64][17];
    #pragma unroll
    for (int r = 0; r < 16; ++r) red[kc][b][r] = acc[r];
    __syncthreads();

    float pre[4];
    #pragma unroll
    for (int g = 0; g < 4; ++g) {
        float ssum = 0.f;
        #pragma unroll
        for (int qq = 0; qq < 4; ++qq) ssum += red[qq][b][g * 4 + kc];
        pre[g] = ssum;
    }

    const int uu = u0 + kc;   // this thread's hidden unit
    const float* gxp = gates + (size_t)dir * (BB * TCH * G4H)
                             + (size_t)(b * TCH + tl) * G4H + uu;
    #pragma unroll
    for (int g = 0; g < 4; ++g) pre[g] += gxp[g * HH];

    const int len  = lengths[b];
    const bool msk = (t < len);

    float* cp = cbuf + (size_t)(dir * BB + b) * KPAD + uu;
    const float cold = *cp;
    const float hold = hpL[(size_t)b * KPAD + uu];

    const float ig = sigm(pre[0]);
    const float fg = sigm(pre[1]);
    const float gg = tanh_fast(pre[2]);
    const float og = sigm(pre[3]);
    const float cn = fg * cold + ig * gg;
    const float hn = og * tanh_fast(cn);

    *cp = msk ? cn : cold;
    hbuf[(size_t)((dir * 2 + (par ^ 1)) * BB + b) * KPAD + uu] = msk ? hn : hold;
    yout[(size_t)(b * TT + t) * y_ld + dir * HH + uu] = msk ? hn : 0.f;
}

extern "C" void kernel_launch(void* const* d_in, const int* in_sizes, int n_in,
                              void* d_out, int out_size, void* d_ws, size_t ws_size,
                              hipStream_t stream)
{
    (void)in_sizes; (void)n_in; (void)out_size; (void)ws_size;

    const float* seqs    = (const float*)d_in[0];
    const int*   lengths = (const int*)  d_in[1];
    const float* W_ih0f  = (const float*)d_in[2];
    const float* W_hh0f  = (const float*)d_in[3];
    const float* b0f     = (const float*)d_in[4];
    const float* W_ih0b  = (const float*)d_in[5];
    const float* W_hh0b  = (const float*)d_in[6];
    const float* b0b     = (const float*)d_in[7];
    const float* W_ih1f  = (const float*)d_in[8];
    const float* W_hh1f  = (const float*)d_in[9];
    const float* b1f     = (const float*)d_in[10];
    const float* W_ih1b  = (const float*)d_in[11];
    const float* W_hh1b  = (const float*)d_in[12];
    const float* b1b     = (const float*)d_in[13];

    // workspace layout (fp32 throughout), ~223 MiB total
    char* ws = (char*)d_ws;
    const size_t SZ_GATES = (size_t)2 * BB * TCH * G4H * 4;       //  65,536,000
    const size_t SZ_OUT0  = (size_t)BB * TT * D1P * 4;            // 134,217,728
    const size_t SZ_WHH   = (size_t)2 * 2 * G4H * KPAD * 4;       //  16,384,000
    const size_t SZ_WIH1  = (size_t)2 * G4H * D1P * 4;            //  16,384,000
    const size_t SZ_HBUF  = (size_t)2 * 2 * BB * KPAD * 4;        //     524,288
    const size_t SZ_CBUF  = (size_t)2 * BB * KPAD * 4;            //     262,144

    float* gatesc  = (float*)(ws);
    float* out0    = (float*)(ws + SZ_GATES);
    float* whhpad  = (float*)(ws + SZ_GATES + SZ_OUT0);
    float* wih1pad = (float*)(ws + SZ_GATES + SZ_OUT0 + SZ_WHH);
    float* hbuf    = (float*)(ws + SZ_GATES + SZ_OUT0 + SZ_WHH + SZ_WIH1);
    float* cbuf    = (float*)(ws + SZ_GATES + SZ_OUT0 + SZ_WHH + SZ_WIH1 + SZ_HBUF);

    // weight prep (re-done every call: ws is re-poisoned before each timed launch)
    pad_whh_kernel<<<16000, 256, 0, stream>>>(W_hh0f, W_hh0b, W_hh1f, W_hh1b, whhpad);
    pad_wih1_kernel<<<16000, 256, 0, stream>>>(W_ih1f, W_ih1b, wih1pad);
    hipMemsetAsync(out0, 0, SZ_OUT0, stream);   // layer-1 input: padded cols + masked zeros

    for (int layer = 0; layer < 2; ++layer) {
        hipMemsetAsync(hbuf, 0, SZ_HBUF, stream);
        hipMemsetAsync(cbuf, 0, SZ_CBUF, stream);

        const float* A    = layer ? out0 : seqs;
        const int    lda  = layer ? D1P : 512;
        const int    K    = layer ? D1P : 512;
        const float* Wf   = layer ? wih1pad                      : W_ih0f;
        const float* Wb   = layer ? wih1pad + (size_t)G4H * D1P  : W_ih0b;
        const float* bf_  = layer ? b1f : b0f;
        const float* bb_  = layer ? b1b : b0b;
        const float* whhL = whhpad + (size_t)layer * 2 * G4H * KPAD;
        float*       yo   = layer ? (float*)d_out : out0;
        const int    y_ld = layer ? 1000 : D1P;

        for (int ph = 0; ph < 8; ++ph) {
            const int t0f = ph * TCH;
            const int t0b = TT - TCH * (ph + 1);
            gemm_chunk_kernel<<<dim3(64, 63, 2), 256, 0, stream>>>(
                A, lda, K, Wf, Wb, bf_, bb_, gatesc, t0f, t0b);
            for (int sl = 0; sl < TCH; ++sl) {
                const int s = ph * TCH + sl;
                lstm_step_kernel<<<dim3(125, 2), 256, 0, stream>>>(
                    gatesc, whhL, lengths, hbuf, cbuf, yo, y_ld, s, ph);
            }
        }
    }
}